// Round 3
// baseline (155.217 us; speedup 1.0000x reference)
//
#include <hip/hip_runtime.h>
#include <hip/hip_cooperative_groups.h>

namespace cg = cooperative_groups;

// loss = sum_ij C[i,j]*(t[i]+t[j]-2*G[i,j]) / (B*(n_pos+1e-8))
//   t[k]  = sum_b P[b,k]^2  (fp32 exact)
//   G     = P^T P via bf16 MFMA (error ~1e-5 rel, threshold 2e-2)
//   n_pos = count(C>0), counted alongside the (single) C read.
//
// Single cooperative kernel, 256 blocks x 256 threads:
//   phase 0: transpose P -> bf16 PT[col][b] in ws, t[col] (fp32) in ws
//   phase 1: per block one 64x64 G tile via mfma_16x16x32_bf16, fragments
//            loaded straight from global (L2-resident, no LDS), fused
//            C-weighted accumulate + n_pos count, per-block partials to ws
//   phase 2: block 0 reduces 256 partials, writes out[0]

#define B_DIM 128
#define N_DIM 1024

typedef __bf16 bf16x8 __attribute__((ext_vector_type(8)));
typedef float  f32x4  __attribute__((ext_vector_type(4)));
typedef short  s16x8  __attribute__((ext_vector_type(8)));

static __device__ inline unsigned short f2bf(float f) {
    union { float f; unsigned u; } v; v.f = f;
    unsigned r = (v.u + 0x7fffu + ((v.u >> 16) & 1u)) >> 16;  // RNE
    return (unsigned short)r;
}

__global__ __launch_bounds__(256) void fused_kernel(const float* __restrict__ P,
                                                    const float* __restrict__ C,
                                                    float* __restrict__ out,
                                                    unsigned short* __restrict__ PT,
                                                    float* __restrict__ tws,
                                                    float* __restrict__ psum,
                                                    unsigned* __restrict__ pcnt) {
    const int tid = threadIdx.x, bid = blockIdx.x;
    const int l = tid & 63, w = tid >> 6;
    __shared__ float    tp[4][4];
    __shared__ float    wsum[4];
    __shared__ unsigned wcnt[4];
    __shared__ double   fsum[4];
    __shared__ unsigned fcnt[4];

    // ---- phase 0: P -> bf16 PT[col][b] + t[col] (block bid owns 4 cols) ----
    {
        const int c = tid & 3, b = tid >> 2;        // b in [0,64), each does b and b+64
        const int col = bid * 4 + c;
        float p0 = P[b * N_DIM + col];
        float p1 = P[(b + 64) * N_DIM + col];
        PT[col * B_DIM + b]      = f2bf(p0);
        PT[col * B_DIM + b + 64] = f2bf(p1);
        float sq = fmaf(p0, p0, p1 * p1);
#pragma unroll
        for (int off = 4; off <= 32; off <<= 1) sq += __shfl_xor(sq, off);
        if (l < 4) tp[w][l] = sq;                   // lanes 0..3 hold c=0..3
        __syncthreads();
        if (tid < 4) tws[bid * 4 + tid] = tp[0][tid] + tp[1][tid] + tp[2][tid] + tp[3][tid];
    }
    __threadfence();
    cg::this_grid().sync();

    // ---- phase 1: one 64x64 G tile per block, fused C apply ----
    const int i0 = (bid >> 4) * 64, j0 = (bid & 15) * 64;
    const s16x8* PT8 = (const s16x8*)PT;

    bf16x8 A[4];
    const int arow = i0 + w * 16 + (l & 15);
#pragma unroll
    for (int s = 0; s < 4; ++s) {
        s16x8 raw = PT8[(arow * B_DIM + s * 32 + (l >> 4) * 8) >> 3];
        A[s] = __builtin_bit_cast(bf16x8, raw);
    }
    float tr[4];
#pragma unroll
    for (int r = 0; r < 4; ++r) tr[r] = tws[i0 + w * 16 + (l >> 4) * 4 + r];

    float loss = 0.f;
    unsigned cnt = 0;
#pragma unroll
    for (int nt = 0; nt < 4; ++nt) {
        const int bcol = j0 + nt * 16 + (l & 15);
        f32x4 acc = {0.f, 0.f, 0.f, 0.f};
#pragma unroll
        for (int s = 0; s < 4; ++s) {
            s16x8 raw = PT8[(bcol * B_DIM + s * 32 + (l >> 4) * 8) >> 3];
            bf16x8 Bf = __builtin_bit_cast(bf16x8, raw);
            acc = __builtin_amdgcn_mfma_f32_16x16x32_bf16(A[s], Bf, acc, 0, 0, 0);
        }
        const float tc = tws[bcol];
#pragma unroll
        for (int r = 0; r < 4; ++r) {
            const int gi = i0 + w * 16 + (l >> 4) * 4 + r;   // C/D: col=lane&15, row=(lane>>4)*4+r
            float cv = C[gi * N_DIM + bcol];
            loss = fmaf(cv, tr[r] + tc - 2.f * acc[r], loss);
            cnt += (cv > 0.f) ? 1u : 0u;
        }
    }

    // per-wave then per-block reduce
#pragma unroll
    for (int off = 32; off > 0; off >>= 1) {
        loss += __shfl_down(loss, off);
        cnt  += __shfl_down(cnt, off);
    }
    if (l == 0) { wsum[w] = loss; wcnt[w] = cnt; }
    __syncthreads();
    if (tid == 0) {
        psum[bid] = wsum[0] + wsum[1] + wsum[2] + wsum[3];
        pcnt[bid] = wcnt[0] + wcnt[1] + wcnt[2] + wcnt[3];
    }
    __threadfence();
    cg::this_grid().sync();

    // ---- phase 2: block 0 final reduce ----
    if (bid == 0) {
        double s = (double)psum[tid];
        unsigned c = pcnt[tid];
#pragma unroll
        for (int off = 32; off > 0; off >>= 1) {
            s += __shfl_down(s, off);
            c += __shfl_down(c, off);
        }
        if (l == 0) { fsum[w] = s; fcnt[w] = c; }
        __syncthreads();
        if (tid == 0) {
            double st = fsum[0] + fsum[1] + fsum[2] + fsum[3];
            double ct = (double)(fcnt[0] + fcnt[1] + fcnt[2] + fcnt[3]);
            out[0] = (float)(st / ((double)B_DIM * (ct + 1e-8)));
        }
    }
}

extern "C" void kernel_launch(void* const* d_in, const int* in_sizes, int n_in,
                              void* d_out, int out_size, void* d_ws, size_t ws_size,
                              hipStream_t stream) {
    const float* probs = (const float*)d_in[0];   // [128, 1024] fp32
    const float* co    = (const float*)d_in[1];   // [1024, 1024] fp32
    float* out = (float*)d_out;

    unsigned short* PT   = (unsigned short*)d_ws;                       // 256 KiB
    float*          tws  = (float*)((char*)d_ws + (256u << 10));        // 4 KiB
    float*          psum = (float*)((char*)d_ws + (260u << 10));        // 1 KiB
    unsigned*       pcnt = (unsigned*)((char*)d_ws + (261u << 10));     // 1 KiB

    void* args[] = {(void*)&probs, (void*)&co, (void*)&out,
                    (void*)&PT, (void*)&tws, (void*)&psum, (void*)&pcnt};
    hipLaunchCooperativeKernel((const void*)fused_kernel, dim3(256), dim3(256),
                               args, 0, stream);
}

// Round 4
// 62.093 us; speedup vs baseline: 2.4998x; 2.4998x over previous
//
#include <hip/hip_runtime.h>

// loss = sum_ij C[i,j]*(t[i]+t[j]-2*G[i,j]) / (B*(n_pos+1e-8))
//   t[k] = sum_b p̂[b,k]^2 (bf16-consistent), G = P^T P via bf16 MFMA.
// Two plain kernels (coop grid.sync was 83us in R3 — never again):
//   tile_kernel: 1024 blocks (32x32 C-tiles) x 256 thr. Per block: transpose
//     both P panels fp32->bf16 into padded LDS, t from staged bf16, 4 MFMA
//     per wave (16x16x32, layouts HW-verified in R3), C loads issued first,
//     per-block partials -> ws.
//   reduce_kernel: 1024 partials -> out.

#define B_DIM 128
#define N_DIM 1024
#define PAD 136   // bf16 row stride: 272 B = 17*16, keeps b128 alignment

typedef __bf16 bf16x8 __attribute__((ext_vector_type(8)));
typedef float  f32x4  __attribute__((ext_vector_type(4)));

static __device__ inline unsigned short f2bf(float f) {
    union { float f; unsigned u; } v; v.f = f;
    return (unsigned short)((v.u + 0x7fffu + ((v.u >> 16) & 1u)) >> 16);  // RNE
}
static __device__ inline float bf2f(unsigned short h) {
    union { unsigned u; float f; } v; v.u = ((unsigned)h) << 16;
    return v.f;
}

__global__ __launch_bounds__(256) void tile_kernel(const float* __restrict__ P,
                                                   const float* __restrict__ C,
                                                   float* __restrict__ psum,
                                                   unsigned* __restrict__ pcnt) {
    __shared__ unsigned short PT[64][PAD];   // rows 0-31: i-panel, 32-63: j-panel
    __shared__ float ts[64];
    __shared__ float wsum[4];
    __shared__ unsigned wcnt[4];

    const int tid = threadIdx.x, bid = blockIdx.x;
    const int l = tid & 63, w = tid >> 6;
    const int i0 = (bid >> 5) * 32, j0 = (bid & 31) * 32;
    const int wr = w >> 1, wc = w & 1;       // wave's 16x16 quadrant

    // ---- issue C loads first (consumed in epilogue; latency hidden) ----
    const int gcol = j0 + wc * 16 + (l & 15);
    float cv0 = C[(i0 + wr * 16 + (l >> 4) * 4 + 0) * N_DIM + gcol];
    float cv1 = C[(i0 + wr * 16 + (l >> 4) * 4 + 1) * N_DIM + gcol];
    float cv2 = C[(i0 + wr * 16 + (l >> 4) * 4 + 2) * N_DIM + gcol];
    float cv3 = C[(i0 + wr * 16 + (l >> 4) * 4 + 3) * N_DIM + gcol];

    // ---- stage both panels: fp32 coalesced reads -> bf16 transposed LDS ----
    const float4* P4 = (const float4*)P;
#pragma unroll
    for (int r = 0; r < 8; ++r) {
        const int pan = (r < 4) ? 0 : 1;
        const int p0  = (r < 4) ? i0 : j0;
        const int b   = (r & 3) * 32 + (tid >> 3);   // batch row
        const int q   = tid & 7;                     // col-quad within panel
        float4 v = P4[b * (N_DIM / 4) + (p0 >> 2) + q];
        PT[pan * 32 + q * 4 + 0][b] = f2bf(v.x);
        PT[pan * 32 + q * 4 + 1][b] = f2bf(v.y);
        PT[pan * 32 + q * 4 + 2][b] = f2bf(v.z);
        PT[pan * 32 + q * 4 + 3][b] = f2bf(v.w);
    }
    __syncthreads();

    // ---- wave 0: t per staged column (bf16-consistent, fp32 accum) ----
    if (tid < 64) {
        float s = 0.f;
#pragma unroll 8
        for (int b = 0; b < B_DIM; ++b) {
            float v = bf2f(PT[tid][b]);
            s = fmaf(v, v, s);
        }
        ts[tid] = s;
    }

    // ---- fragments + MFMA (layouts HW-verified in R3) ----
    f32x4 acc = {0.f, 0.f, 0.f, 0.f};
    const int ar = wr * 16 + (l & 15);         // i-panel LDS row
    const int br = 32 + wc * 16 + (l & 15);    // j-panel LDS row
    const int ko = (l >> 4) * 8;
#pragma unroll
    for (int s = 0; s < 4; ++s) {
        bf16x8 af = *(const bf16x8*)&PT[ar][s * 32 + ko];
        bf16x8 bf = *(const bf16x8*)&PT[br][s * 32 + ko];
        acc = __builtin_amdgcn_mfma_f32_16x16x32_bf16(af, bf, acc, 0, 0, 0);
    }
    __syncthreads();   // ts visible to all

    // ---- epilogue: C*(ti+tj-2G) + count ----
    const float tj = ts[32 + wc * 16 + (l & 15)];
    float loss = 0.f;
    unsigned cnt = 0;
    {
        const int rb = wr * 16 + (l >> 4) * 4;
        loss = fmaf(cv0, ts[rb + 0] + tj - 2.f * acc[0], loss);
        loss = fmaf(cv1, ts[rb + 1] + tj - 2.f * acc[1], loss);
        loss = fmaf(cv2, ts[rb + 2] + tj - 2.f * acc[2], loss);
        loss = fmaf(cv3, ts[rb + 3] + tj - 2.f * acc[3], loss);
        cnt = (cv0 > 0.f) + (cv1 > 0.f) + (cv2 > 0.f) + (cv3 > 0.f);
    }
#pragma unroll
    for (int off = 32; off > 0; off >>= 1) {
        loss += __shfl_down(loss, off);
        cnt  += __shfl_down(cnt, off);
    }
    if (l == 0) { wsum[w] = loss; wcnt[w] = cnt; }
    __syncthreads();
    if (tid == 0) {
        psum[bid] = wsum[0] + wsum[1] + wsum[2] + wsum[3];
        pcnt[bid] = wcnt[0] + wcnt[1] + wcnt[2] + wcnt[3];
    }
}

__global__ __launch_bounds__(256) void reduce_kernel(const float* __restrict__ psum,
                                                     const unsigned* __restrict__ pcnt,
                                                     float* __restrict__ out) {
    __shared__ double ws_[4];
    __shared__ unsigned wc_[4];
    const int tid = threadIdx.x;
    double s = 0.0; unsigned c = 0;
#pragma unroll
    for (int r = 0; r < 4; ++r) {
        s += (double)psum[r * 256 + tid];
        c += pcnt[r * 256 + tid];
    }
#pragma unroll
    for (int off = 32; off > 0; off >>= 1) {
        s += __shfl_down(s, off);
        c += __shfl_down(c, off);
    }
    const int wave = tid >> 6, lane = tid & 63;
    if (lane == 0) { ws_[wave] = s; wc_[wave] = c; }
    __syncthreads();
    if (tid == 0) {
        double st = ws_[0] + ws_[1] + ws_[2] + ws_[3];
        double ct = (double)(wc_[0] + wc_[1] + wc_[2] + wc_[3]);
        out[0] = (float)(st / ((double)B_DIM * (ct + 1e-8)));
    }
}

extern "C" void kernel_launch(void* const* d_in, const int* in_sizes, int n_in,
                              void* d_out, int out_size, void* d_ws, size_t ws_size,
                              hipStream_t stream) {
    const float* probs = (const float*)d_in[0];   // [128, 1024] fp32
    const float* co    = (const float*)d_in[1];   // [1024, 1024] fp32
    float* out = (float*)d_out;

    float*    psum = (float*)d_ws;                        // 1024 * 4 B
    unsigned* pcnt = (unsigned*)((char*)d_ws + 4096);     // 1024 * 4 B

    tile_kernel<<<1024, 256, 0, stream>>>(probs, co, psum, pcnt);
    reduce_kernel<<<1, 256, 0, stream>>>(psum, pcnt, out);
}